// Round 5
// baseline (565.980 us; speedup 1.0000x reference)
//
#include <hip/hip_runtime.h>
#include <hip/hip_bf16.h>
#include <stdint.h>

#define SEQ 2048
#define HIDDEN 4096
#define NHEAD 32
#define NKVH 8
#define HDIM 128
#define NQT (SEQ / 64)
#define SCALE 0.08838834764831845f
#define QKV_N ((NHEAD + 2 * NKVH) * HDIM)   /* 6144 */
#define NT64 (HIDDEN / 64)                  /* 64 K-tiles */

typedef __bf16 bf16x8 __attribute__((ext_vector_type(8)));
typedef float floatx4 __attribute__((ext_vector_type(4)));

__device__ inline float bf2f(unsigned int u16) {
    union { unsigned int i; float f; } x;
    x.i = u16 << 16;
    return x.f;
}
__device__ inline unsigned short f2bf(float f) {
    union { float f; unsigned int u; } x;
    x.f = f;
    unsigned int r = x.u + 0x7FFF + ((x.u >> 16) & 1);   // RNE; finite inputs
    return (unsigned short)(r >> 16);
}

// fp32 -> bf16 cast, 4 elems/thread
__global__ __launch_bounds__(256) void cast_f32_bf16(const float* __restrict__ s,
                                                     unsigned short* __restrict__ d, int n4) {
    int i = blockIdx.x * 256 + threadIdx.x;
    if (i < n4) {
        float4 v = ((const float4*)s)[i];
        ushort4 o;
        o.x = f2bf(v.x); o.y = f2bf(v.y); o.z = f2bf(v.z); o.w = f2bf(v.w);
        ((ushort4*)d)[i] = o;
    }
}

__device__ inline void storeC(float* p, float v) { *p = v; }
__device__ inline void storeC(unsigned short* p, float v) { *p = f2bf(v); }

// async 16B global->LDS; within a wave LDS dest must be base + lane*16
#define GLL16(gp, lp) __builtin_amdgcn_global_load_lds( \
    (const __attribute__((address_space(1))) unsigned int*)(gp), \
    (__attribute__((address_space(3))) unsigned int*)(lp), 16, 0, 0)

// C[m][n] = sum_k A[m][k]*B[n][k]; 128x128 tile, BK=32, 2ph dbuf (O-projection).
template <typename OutT>
__global__ __launch_bounds__(256) void gemm_nt_mfma(const unsigned short* __restrict__ A,
                                                    const unsigned short* __restrict__ B,
                                                    OutT* __restrict__ C,
                                                    int M, int N, int K) {
    __shared__ unsigned short As[2][128 * 32];
    __shared__ unsigned short Bs[2][128 * 32];
    const int tid = threadIdx.x;
    const int lane = tid & 63;
    const int w = tid >> 6;
    const int m0 = blockIdx.y * 128, n0 = blockIdx.x * 128;
    const int wr = (w >> 1) * 64, wc = (w & 1) * 64;
    const int srow = tid >> 2;
    const int scol = (tid & 3) * 8;
    const int quad = lane >> 4, l16 = lane & 15;

    auto stage = [&](int buf, int k0) {
        const unsigned short* gA = A + (size_t)(m0 + srow) * K + k0 + scol;
        const unsigned short* gB = B + (size_t)(n0 + srow) * K + k0 + scol;
        GLL16(gA,                  &As[buf][srow * 32 + scol]);
        GLL16(gA + (size_t)64 * K, &As[buf][(64 + srow) * 32 + scol]);
        GLL16(gB,                  &Bs[buf][srow * 32 + scol]);
        GLL16(gB + (size_t)64 * K, &Bs[buf][(64 + srow) * 32 + scol]);
    };

    floatx4 acc[4][4] = {};

    stage(0, 0);
    __syncthreads();
    int cur = 0;

    for (int k0 = 0; k0 < K; k0 += 32) {
        if (k0 + 32 < K) stage(cur ^ 1, k0 + 32);

        bf16x8 af[4], bg[4];
        #pragma unroll
        for (int i = 0; i < 4; ++i)
            af[i] = *(const bf16x8*)(&As[cur][(wr + i * 16 + l16) * 32 + quad * 8]);
        #pragma unroll
        for (int j = 0; j < 4; ++j)
            bg[j] = *(const bf16x8*)(&Bs[cur][(wc + j * 16 + l16) * 32 + quad * 8]);
        #pragma unroll
        for (int i = 0; i < 4; ++i)
            #pragma unroll
            for (int j = 0; j < 4; ++j)
                acc[i][j] = __builtin_amdgcn_mfma_f32_16x16x32_bf16(af[i], bg[j], acc[i][j], 0, 0, 0);

        __syncthreads();
        cur ^= 1;
    }

    #pragma unroll
    for (int i = 0; i < 4; ++i) {
        #pragma unroll
        for (int j = 0; j < 4; ++j) {
            int col = n0 + wc + j * 16 + l16;
            int rowb = m0 + wr + i * 16 + quad * 4;
            #pragma unroll
            for (int r = 0; r < 4; ++r)
                storeC(&C[(size_t)(rowb + r) * N + col], acc[i][j][r]);
        }
    }
}

// ---------------------------------------------------------------------------
// Fused QKV projection, 256x256 tile, BK=64, 8-phase-per-2-K-tiles schedule
// (plain-HIP port of the m201 template). 512 threads = 8 waves (2M x 4N),
// per-wave 128x64 output (acc[8][4]). LDS 128 KiB: 2 K-tile double buffer.
// Both-sides swizzle: LDS dest linear (GLL16-legal); chunk XOR (c ^ (row&7))
// applied on global source AND ds_read address (same involution as attn_mfma).
// Counted vmcnt: stage order {s0,s2},{s4,s5},{s6,s7},{s1,s3}; vmcnt(4) after
// phase 1 (drains prev-tile s1/s3 needed by phase 2), vmcnt(2) after phase 3
// (leaves next-tile s1/s3 in flight across the K-tile boundary). Raw
// s_barrier only (no __syncthreads vmcnt(0) drain). setprio(1) around MFMAs.
// B rows: [0,4096)=wq, [4096,5120)=wk, [5120,6144)=wv. Epilogue block-uniform
// on n0: Q normal, K normal (ld 1024), V transposed bf16 (ushort4 stores).
// ---------------------------------------------------------------------------
__global__ __launch_bounds__(512, 2) void gemm_qkv_8ph(const unsigned short* __restrict__ A,
                                                       const unsigned short* __restrict__ B,
                                                       unsigned short* __restrict__ Cq,
                                                       unsigned short* __restrict__ Ck,
                                                       unsigned short* __restrict__ Cvt) {
    constexpr int K = HIDDEN;
    __shared__ unsigned short As[2][256 * 64];
    __shared__ unsigned short Bs[2][256 * 64];
    const int tid = threadIdx.x;
    const int lane = tid & 63;
    const int w = tid >> 6;
    const int wm = w >> 2, wn = w & 3;
    const int quad = lane >> 4, l16 = lane & 15;
    const int m0 = blockIdx.y * 256, n0 = blockIdx.x * 256;

    // stage call s: s<4 -> A rows [s*64, s*64+64); s>=4 -> B rows [(s-4)*64, ...).
    // Per call: 512 threads x 16B = 64 rows. LDS byte = rbase*128 + tid*16 (linear
    // per wave); global chunk pre-swizzled so ds_read-side XOR reads it back.
    auto stg = [&](int buf, int kt, int s) {
        const int rb = (s & 3) * 64;
        const int r = rb + (tid >> 3);
        const int cg = (tid & 7) ^ (r & 7);
        if (s < 4) {
            const unsigned short* gp = A + (size_t)(m0 + r) * K + kt * 64 + cg * 8;
            GLL16(gp, &As[buf][r * 64 + (tid & 7) * 8]);
        } else {
            const unsigned short* gp = B + (size_t)(n0 + r) * K + kt * 64 + cg * 8;
            GLL16(gp, &Bs[buf][r * 64 + (tid & 7) * 8]);
        }
    };

    floatx4 acc[8][4] = {};

    // prologue: stage K-tile 0 into buf0, full drain once
    #pragma unroll
    for (int s = 0; s < 8; ++s) stg(0, 0, s);
    asm volatile("s_waitcnt vmcnt(0)" ::: "memory");
    __builtin_amdgcn_s_barrier();
    asm volatile("" ::: "memory");

    auto ktile = [&](int cur, int tnext, bool hasNext) {
        // stage order: everything needed at next tile's phase 0 first; A-mid
        // halves (s1: rows 64-127, s3: rows 192-255, first needed at phase 2) last.
        constexpr int SL[8] = {0, 2, 4, 5, 6, 7, 1, 3};
        #pragma unroll
        for (int p = 0; p < 4; ++p) {
            const int qm = p >> 1, qn = p & 1;   // quadrant: M-half, N-half of wave tile
            bf16x8 af[4][2], bg[2][2];
            #pragma unroll
            for (int i2 = 0; i2 < 4; ++i2) {
                const int row = wm * 128 + qm * 64 + i2 * 16 + l16;
                #pragma unroll
                for (int kk = 0; kk < 2; ++kk)
                    af[i2][kk] = *(const bf16x8*)(&As[cur][row * 64 + (((kk * 4 + quad) ^ (row & 7)) * 8)]);
            }
            #pragma unroll
            for (int j2 = 0; j2 < 2; ++j2) {
                const int brow = wn * 64 + qn * 32 + j2 * 16 + l16;
                #pragma unroll
                for (int kk = 0; kk < 2; ++kk)
                    bg[j2][kk] = *(const bf16x8*)(&Bs[cur][brow * 64 + (((kk * 4 + quad) ^ (brow & 7)) * 8)]);
            }
            if (hasNext) { stg(cur ^ 1, tnext, SL[2 * p]); stg(cur ^ 1, tnext, SL[2 * p + 1]); }
            __builtin_amdgcn_s_barrier();
            asm volatile("" ::: "memory");
            __builtin_amdgcn_s_setprio(1);
            #pragma unroll
            for (int i2 = 0; i2 < 4; ++i2)
                #pragma unroll
                for (int j2 = 0; j2 < 2; ++j2)
                    #pragma unroll
                    for (int kk = 0; kk < 2; ++kk)
                        acc[qm * 4 + i2][qn * 2 + j2] = __builtin_amdgcn_mfma_f32_16x16x32_bf16(
                            af[i2][kk], bg[j2][kk], acc[qm * 4 + i2][qn * 2 + j2], 0, 0, 0);
            __builtin_amdgcn_s_setprio(0);
            if (p == 1) {   // before phase 2 reads cur-tile s1/s3: drain 2 oldest
                if (hasNext) asm volatile("s_waitcnt vmcnt(4)" ::: "memory");
                else         asm volatile("s_waitcnt vmcnt(0)" ::: "memory");
            }
            if (p == 3) {   // tile boundary: complete next-tile s0,s2,s4-s7; keep s1,s3 in flight
                if (hasNext) asm volatile("s_waitcnt vmcnt(2)" ::: "memory");
                else         asm volatile("s_waitcnt vmcnt(0)" ::: "memory");
            }
            __builtin_amdgcn_s_barrier();
            asm volatile("" ::: "memory");
        }
    };

    for (int tp = 0; tp < NT64 / 2; ++tp) {
        ktile(0, 2 * tp + 1, true);
        ktile(1, 2 * tp + 2, tp < NT64 / 2 - 1);
    }

    // epilogue: C/D layout col = l16, row = quad*4 + r (per 16x16 fragment)
    if (n0 < NHEAD * HDIM) {                       // Q segment
        const int N = NHEAD * HDIM;
        #pragma unroll
        for (int i = 0; i < 8; ++i)
            #pragma unroll
            for (int j = 0; j < 4; ++j) {
                const int col = n0 + wn * 64 + j * 16 + l16;
                const int rowb = m0 + wm * 128 + i * 16 + quad * 4;
                #pragma unroll
                for (int r = 0; r < 4; ++r)
                    Cq[(size_t)(rowb + r) * N + col] = f2bf(acc[i][j][r]);
            }
    } else if (n0 < (NHEAD + NKVH) * HDIM) {       // K segment
        const int N = NKVH * HDIM;
        #pragma unroll
        for (int i = 0; i < 8; ++i)
            #pragma unroll
            for (int j = 0; j < 4; ++j) {
                const int col = n0 - NHEAD * HDIM + wn * 64 + j * 16 + l16;
                const int rowb = m0 + wm * 128 + i * 16 + quad * 4;
                #pragma unroll
                for (int r = 0; r < 4; ++r)
                    Ck[(size_t)(rowb + r) * N + col] = f2bf(acc[i][j][r]);
            }
    } else {                                       // V segment (transposed out)
        #pragma unroll
        for (int i = 0; i < 8; ++i)
            #pragma unroll
            for (int j = 0; j < 4; ++j) {
                const int col = n0 - (NHEAD + NKVH) * HDIM + wn * 64 + j * 16 + l16;
                const int rowb = m0 + wm * 128 + i * 16 + quad * 4;
                ushort4 pk;
                pk.x = f2bf(acc[i][j][0]);
                pk.y = f2bf(acc[i][j][1]);
                pk.z = f2bf(acc[i][j][2]);
                pk.w = f2bf(acc[i][j][3]);
                *(ushort4*)&Cvt[(size_t)col * SEQ + rowb] = pk;
            }
    }
}

// In-place RoPE on bf16 [SEQ][nh*HDIM]; cos/sin fp32, cos[s][d]==cos[s][d+64].
__global__ __launch_bounds__(256) void rope_bf16(unsigned short* __restrict__ x,
                                                 const float* __restrict__ cosb,
                                                 const float* __restrict__ sinb,
                                                 int nh) {
    int idx = blockIdx.x * 256 + threadIdx.x;
    int d = idx & 63;
    int t = idx >> 6;
    int h = t % nh;
    int s = t / nh;
    float cs = cosb[s * HDIM + d];
    float sn = sinb[s * HDIM + d];
    unsigned short* p = x + (size_t)s * nh * HDIM + h * HDIM + d;
    float x1 = bf2f(p[0]), x2 = bf2f(p[64]);
    p[0]  = f2bf(x1 * cs - x2 * sn);
    p[64] = f2bf(x2 * cs + x1 * sn);
}

// MFMA flash attention. grid (NQT/2, NHEAD), block 256 (4 waves).
// Work-balanced qt pairing + double-buffered K/V staging (validated R3).
__global__ __launch_bounds__(256) void attn_mfma(const unsigned short* __restrict__ qg,
                                                 const unsigned short* __restrict__ kgb,
                                                 const unsigned short* __restrict__ vtg,
                                                 unsigned short* __restrict__ ao) {
    __shared__ unsigned short Ks[2][64 * 128];   // [key][dim], chunk-swizzled, dbuf
    __shared__ unsigned short Vs[2][128 * 64];   // [dim][key], chunk-swizzled, dbuf
    __shared__ unsigned short Ps[4][16 * 64];    // wave-private P, chunk-swizzled
    const int h = blockIdx.y;
    const int kvh = h >> 2;                   // NHEAD/NKVH = 4
    const int tid = threadIdx.x;
    const int w = tid >> 6, lane = tid & 63;
    const int quad = lane >> 4, l16 = lane & 15;
    const int srow16 = tid >> 4, sc16 = tid & 15;   // K staging: 16 rows x 16 chunks / call
    const int sdim8 = tid >> 3, skc8 = tid & 7;     // V staging: 32 dims x 8 chunks / call

    auto stage = [&](int buf, int t) {
        #pragma unroll
        for (int rl = 0; rl < 4; ++rl) {
            int key = rl * 16 + srow16;
            int cg = sc16 ^ (key & 7);   // swizzle on global side
            const unsigned short* gp = kgb + (size_t)(t * 64 + key) * (NKVH * HDIM) + kvh * HDIM + cg * 8;
            GLL16(gp, &Ks[buf][key * 128 + sc16 * 8]);
        }
        #pragma unroll
        for (int rl = 0; rl < 4; ++rl) {
            int dim = rl * 32 + sdim8;
            int kg2 = skc8 ^ (dim & 7);
            const unsigned short* gp = vtg + (size_t)(kvh * HDIM + dim) * SEQ + t * 64 + kg2 * 8;
            GLL16(gp, &Vs[buf][dim * 64 + skc8 * 8]);
        }
    };

    #pragma unroll 1
    for (int ph = 0; ph < 2; ++ph) {
        const int qt = ph ? (NQT - 1 - (int)blockIdx.x) : (int)blockIdx.x;
        const int s0 = qt * 64;

        bf16x8 aq[4];
        {
            const unsigned short* qrowp = qg + (size_t)(s0 + w * 16 + l16) * (NHEAD * HDIM) + h * HDIM;
            #pragma unroll
            for (int ks = 0; ks < 4; ++ks)
                aq[ks] = *(const bf16x8*)(qrowp + ks * 32 + quad * 8);
        }

        floatx4 acc_o[8] = {};
        float m_r[4], l_r[4];
        #pragma unroll
        for (int r = 0; r < 4; ++r) { m_r[r] = -1e30f; l_r[r] = 0.f; }

        stage(0, 0);
        __syncthreads();
        int cur = 0;

        for (int t = 0; t <= qt; ++t) {
            if (t < qt) stage(cur ^ 1, t + 1);
            const unsigned short* Kc = &Ks[cur][0];
            const unsigned short* Vc = &Vs[cur][0];

            floatx4 acc_s[4] = {};
            #pragma unroll
            for (int ks = 0; ks < 4; ++ks)
                #pragma unroll
                for (int jt = 0; jt < 4; ++jt) {
                    bf16x8 bk = *(const bf16x8*)(Kc + (jt * 16 + l16) * 128 +
                                                 (((ks * 4 + quad) ^ (l16 & 7)) * 8));
                    acc_s[jt] = __builtin_amdgcn_mfma_f32_16x16x32_bf16(aq[ks], bk, acc_s[jt], 0, 0, 0);
                }

            float s_v[4][4];
            #pragma unroll
            for (int jt = 0; jt < 4; ++jt)
                #pragma unroll
                for (int r = 0; r < 4; ++r)
                    s_v[jt][r] = acc_s[jt][r] * SCALE;
            if (t == qt) {
                #pragma unroll
                for (int jt = 0; jt < 4; ++jt) {
                    int key = t * 64 + jt * 16 + l16;
                    #pragma unroll
                    for (int r = 0; r < 4; ++r) {
                        int qrow = s0 + w * 16 + quad * 4 + r;
                        if (key > qrow) s_v[jt][r] = -1e30f;
                    }
                }
            }

            float p_v[4][4];
            #pragma unroll
            for (int r = 0; r < 4; ++r) {
                float v = fmaxf(fmaxf(s_v[0][r], s_v[1][r]), fmaxf(s_v[2][r], s_v[3][r]));
                #pragma unroll
                for (int off = 1; off < 16; off <<= 1) v = fmaxf(v, __shfl_xor(v, off));
                float mn = fmaxf(m_r[r], v);
                float alpha = __expf(m_r[r] - mn);
                m_r[r] = mn;
                float sum = 0.f;
                #pragma unroll
                for (int jt = 0; jt < 4; ++jt) { p_v[jt][r] = __expf(s_v[jt][r] - mn); sum += p_v[jt][r]; }
                #pragma unroll
                for (int off = 1; off < 16; off <<= 1) sum += __shfl_xor(sum, off);
                l_r[r] = l_r[r] * alpha + sum;
                #pragma unroll
                for (int nt = 0; nt < 8; ++nt) acc_o[nt][r] *= alpha;
            }

            unsigned short* pw = Ps[w];
            #pragma unroll
            for (int jt = 0; jt < 4; ++jt)
                #pragma unroll
                for (int r = 0; r < 4; ++r) {
                    int row = quad * 4 + r;
                    int c = (2 * jt + (l16 >> 3)) ^ (row & 7);
                    pw[row * 64 + c * 8 + (l16 & 7)] = f2bf(p_v[jt][r]);
                }
            #pragma unroll
            for (int ks = 0; ks < 2; ++ks) {
                bf16x8 ap = *(const bf16x8*)(pw + l16 * 64 + (((ks * 4 + quad) ^ (l16 & 7)) * 8));
                #pragma unroll
                for (int nt = 0; nt < 8; ++nt) {
                    bf16x8 bv = *(const bf16x8*)(Vc + (nt * 16 + l16) * 64 +
                                                 (((ks * 4 + quad) ^ (l16 & 7)) * 8));
                    acc_o[nt] = __builtin_amdgcn_mfma_f32_16x16x32_bf16(ap, bv, acc_o[nt], 0, 0, 0);
                }
            }

            __syncthreads();
            cur ^= 1;
        }

        #pragma unroll
        for (int r = 0; r < 4; ++r) {
            float inv = 1.f / l_r[r];
            int qrow = s0 + w * 16 + quad * 4 + r;
            unsigned short* op = ao + (size_t)qrow * (NHEAD * HDIM) + h * HDIM + l16;
            #pragma unroll
            for (int nt = 0; nt < 8; ++nt)
                op[nt * 16] = f2bf(acc_o[nt][r] * inv);
        }
    }
}

extern "C" void kernel_launch(void* const* d_in, const int* in_sizes, int n_in,
                              void* d_out, int out_size, void* d_ws, size_t ws_size,
                              hipStream_t stream) {
    const float* hidden = (const float*)d_in[0];
    const float* cosb   = (const float*)d_in[1];
    const float* sinb   = (const float*)d_in[2];
    const float* wq     = (const float*)d_in[3];
    const float* wk     = (const float*)d_in[4];
    const float* wv     = (const float*)d_in[5];
    const float* wo     = (const float*)d_in[6];
    // d_in[7..9]: k_cache/v_cache/block_ids — scatter+gather by same ids == identity; unused.

    unsigned short* hb   = (unsigned short*)d_ws;                  // hidden bf16; reused as attn out
    unsigned short* wqkv = hb + (size_t)SEQ * HIDDEN;              // [6144][4096] bf16 (wq;wk;wv); reused for wo
    unsigned short* qb   = wqkv + (size_t)QKV_N * HIDDEN;          // q bf16 [SEQ][4096]
    unsigned short* kb   = qb + (size_t)SEQ * NHEAD * HDIM;        // k bf16 [SEQ][1024]
    unsigned short* vtb  = kb + (size_t)SEQ * NKVH * HDIM;         // v^T bf16 [1024][SEQ]
    unsigned short* ao   = hb;

    dim3 blk(256);
    cast_f32_bf16<<<dim3(SEQ * HIDDEN / 1024), blk, 0, stream>>>(hidden, hb, SEQ * HIDDEN / 4);

    // Cast wq/wk/wv into one stacked weight buffer: rows [0,4096)=wq, [4096,5120)=wk, [5120,6144)=wv
    cast_f32_bf16<<<dim3(HIDDEN * HIDDEN / 1024), blk, 0, stream>>>(wq, wqkv, HIDDEN * HIDDEN / 4);
    cast_f32_bf16<<<dim3(NKVH * HDIM * HIDDEN / 1024), blk, 0, stream>>>(
        wk, wqkv + (size_t)NHEAD * HDIM * HIDDEN, NKVH * HDIM * HIDDEN / 4);
    cast_f32_bf16<<<dim3(NKVH * HDIM * HIDDEN / 1024), blk, 0, stream>>>(
        wv, wqkv + (size_t)(NHEAD + NKVH) * HDIM * HIDDEN, NKVH * HDIM * HIDDEN / 4);

    // Fused QKV projection, 8-phase 256^2 schedule: grid 24x8 = 192 WGs, 512 thr
    gemm_qkv_8ph<<<dim3(QKV_N / 256, SEQ / 256), dim3(512), 0, stream>>>(
        hb, wqkv, qb, kb, vtb);

    // RoPE on q and k
    rope_bf16<<<dim3(SEQ * NHEAD * 64 / 256), blk, 0, stream>>>(qb, cosb, sinb, NHEAD);
    rope_bf16<<<dim3(SEQ * NKVH * 64 / 256), blk, 0, stream>>>(kb, cosb, sinb, NKVH);

    // MFMA flash attention (work-balanced qt pairing, double-buffered staging)
    attn_mfma<<<dim3(NQT / 2, NHEAD), blk, 0, stream>>>(qb, kb, vtb, ao);

    // output projection (fp32 out)
    cast_f32_bf16<<<dim3(HIDDEN * HIDDEN / 1024), blk, 0, stream>>>(wo, wqkv, HIDDEN * HIDDEN / 4);
    gemm_nt_mfma<float><<<dim3(HIDDEN / 128, SEQ / 128), blk, 0, stream>>>(
        ao, wqkv, (float*)d_out, SEQ, HIDDEN, NHEAD * HDIM);
}

// Round 6
// 539.803 us; speedup vs baseline: 1.0485x; 1.0485x over previous
//
#include <hip/hip_runtime.h>
#include <hip/hip_bf16.h>
#include <stdint.h>

#define SEQ 2048
#define HIDDEN 4096
#define NHEAD 32
#define NKVH 8
#define HDIM 128
#define NQT (SEQ / 64)
#define SCALE 0.08838834764831845f
#define QKV_N ((NHEAD + 2 * NKVH) * HDIM)   /* 6144 */

typedef __bf16 bf16x8 __attribute__((ext_vector_type(8)));
typedef float floatx4 __attribute__((ext_vector_type(4)));

__device__ inline float bf2f(unsigned int u16) {
    union { unsigned int i; float f; } x;
    x.i = u16 << 16;
    return x.f;
}
__device__ inline unsigned short f2bf(float f) {
    union { float f; unsigned int u; } x;
    x.f = f;
    unsigned int r = x.u + 0x7FFF + ((x.u >> 16) & 1);   // RNE; finite inputs
    return (unsigned short)(r >> 16);
}

__device__ inline void storeC(float* p, float v) { *p = v; }
__device__ inline void storeC(unsigned short* p, float v) { *p = f2bf(v); }

// async 16B global->LDS; within a wave LDS dest must be base + lane*16
#define GLL16(gp, lp) __builtin_amdgcn_global_load_lds( \
    (const __attribute__((address_space(1))) unsigned int*)(gp), \
    (__attribute__((address_space(3))) unsigned int*)(lp), 16, 0, 0)

// 4-segment fused fp32->bf16 cast. Segment sizes are multiples of 256 float4,
// so each block maps to exactly one segment, no bounds checks.
__global__ __launch_bounds__(256) void cast4_f32_bf16(const float* __restrict__ s0, unsigned short* __restrict__ d0, int nb0,
                                                      const float* __restrict__ s1, unsigned short* __restrict__ d1, int nb1,
                                                      const float* __restrict__ s2, unsigned short* __restrict__ d2, int nb2,
                                                      const float* __restrict__ s3, unsigned short* __restrict__ d3) {
    int b = blockIdx.x;
    const float* s; unsigned short* d; int rel;
    if (b < nb0)                 { s = s0; d = d0; rel = b; }
    else if (b < nb0 + nb1)      { s = s1; d = d1; rel = b - nb0; }
    else if (b < nb0 + nb1 + nb2){ s = s2; d = d2; rel = b - nb0 - nb1; }
    else                         { s = s3; d = d3; rel = b - nb0 - nb1 - nb2; }
    int i = rel * 256 + threadIdx.x;
    float4 v = ((const float4*)s)[i];
    ushort4 o;
    o.x = f2bf(v.x); o.y = f2bf(v.y); o.z = f2bf(v.z); o.w = f2bf(v.w);
    ((ushort4*)d)[i] = o;
}

// single-buffer cast (wo, issued after QKV GEMM frees wqkv)
__global__ __launch_bounds__(256) void cast_f32_bf16(const float* __restrict__ s,
                                                     unsigned short* __restrict__ d, int n4) {
    int i = blockIdx.x * 256 + threadIdx.x;
    if (i < n4) {
        float4 v = ((const float4*)s)[i];
        ushort4 o;
        o.x = f2bf(v.x); o.y = f2bf(v.y); o.z = f2bf(v.z); o.w = f2bf(v.w);
        ((ushort4*)d)[i] = o;
    }
}

// C[m][n] = sum_k A[m][k]*B[n][k]; 128x128 tile, BK=32, 2ph dbuf (O-projection).
template <typename OutT>
__global__ __launch_bounds__(256) void gemm_nt_mfma(const unsigned short* __restrict__ A,
                                                    const unsigned short* __restrict__ B,
                                                    OutT* __restrict__ C,
                                                    int M, int N, int K) {
    __shared__ unsigned short As[2][128 * 32];
    __shared__ unsigned short Bs[2][128 * 32];
    const int tid = threadIdx.x;
    const int lane = tid & 63;
    const int w = tid >> 6;
    const int m0 = blockIdx.y * 128, n0 = blockIdx.x * 128;
    const int wr = (w >> 1) * 64, wc = (w & 1) * 64;
    const int srow = tid >> 2;
    const int scol = (tid & 3) * 8;
    const int quad = lane >> 4, l16 = lane & 15;

    auto stage = [&](int buf, int k0) {
        const unsigned short* gA = A + (size_t)(m0 + srow) * K + k0 + scol;
        const unsigned short* gB = B + (size_t)(n0 + srow) * K + k0 + scol;
        GLL16(gA,                  &As[buf][srow * 32 + scol]);
        GLL16(gA + (size_t)64 * K, &As[buf][(64 + srow) * 32 + scol]);
        GLL16(gB,                  &Bs[buf][srow * 32 + scol]);
        GLL16(gB + (size_t)64 * K, &Bs[buf][(64 + srow) * 32 + scol]);
    };

    floatx4 acc[4][4] = {};

    stage(0, 0);
    __syncthreads();
    int cur = 0;

    for (int k0 = 0; k0 < K; k0 += 32) {
        if (k0 + 32 < K) stage(cur ^ 1, k0 + 32);

        bf16x8 af[4], bg[4];
        #pragma unroll
        for (int i = 0; i < 4; ++i)
            af[i] = *(const bf16x8*)(&As[cur][(wr + i * 16 + l16) * 32 + quad * 8]);
        #pragma unroll
        for (int j = 0; j < 4; ++j)
            bg[j] = *(const bf16x8*)(&Bs[cur][(wc + j * 16 + l16) * 32 + quad * 8]);
        #pragma unroll
        for (int i = 0; i < 4; ++i)
            #pragma unroll
            for (int j = 0; j < 4; ++j)
                acc[i][j] = __builtin_amdgcn_mfma_f32_16x16x32_bf16(af[i], bg[j], acc[i][j], 0, 0, 0);

        __syncthreads();
        cur ^= 1;
    }

    #pragma unroll
    for (int i = 0; i < 4; ++i) {
        #pragma unroll
        for (int j = 0; j < 4; ++j) {
            int col = n0 + wc + j * 16 + l16;
            int rowb = m0 + wr + i * 16 + quad * 4;
            #pragma unroll
            for (int r = 0; r < 4; ++r)
                storeC(&C[(size_t)(rowb + r) * N + col], acc[i][j][r]);
        }
    }
}

// Fused Q+K+V projection GEMM (R4-verified, 133 us). A: [SEQ][HIDDEN] bf16;
// B: [6144][HIDDEN] bf16, rows [0,4096)=wq, [4096,5120)=wk, [5120,6144)=wv.
// 128x128 tile, BK=32, 2ph dbuf. Epilogue routes block-uniformly on n0.
__global__ __launch_bounds__(256) void gemm_qkv_mfma(const unsigned short* __restrict__ A,
                                                     const unsigned short* __restrict__ B,
                                                     unsigned short* __restrict__ Cq,
                                                     unsigned short* __restrict__ Ck,
                                                     unsigned short* __restrict__ Cvt) {
    const int M = SEQ, K = HIDDEN;
    __shared__ unsigned short As[2][128 * 32];
    __shared__ unsigned short Bs[2][128 * 32];
    const int tid = threadIdx.x;
    const int lane = tid & 63;
    const int w = tid >> 6;
    const int m0 = blockIdx.y * 128, n0 = blockIdx.x * 128;
    const int wr = (w >> 1) * 64, wc = (w & 1) * 64;
    const int srow = tid >> 2;
    const int scol = (tid & 3) * 8;
    const int quad = lane >> 4, l16 = lane & 15;

    auto stage = [&](int buf, int k0) {
        const unsigned short* gA = A + (size_t)(m0 + srow) * K + k0 + scol;
        const unsigned short* gB = B + (size_t)(n0 + srow) * K + k0 + scol;
        GLL16(gA,                  &As[buf][srow * 32 + scol]);
        GLL16(gA + (size_t)64 * K, &As[buf][(64 + srow) * 32 + scol]);
        GLL16(gB,                  &Bs[buf][srow * 32 + scol]);
        GLL16(gB + (size_t)64 * K, &Bs[buf][(64 + srow) * 32 + scol]);
    };

    floatx4 acc[4][4] = {};

    stage(0, 0);
    __syncthreads();
    int cur = 0;

    for (int k0 = 0; k0 < K; k0 += 32) {
        if (k0 + 32 < K) stage(cur ^ 1, k0 + 32);

        bf16x8 af[4], bg[4];
        #pragma unroll
        for (int i = 0; i < 4; ++i)
            af[i] = *(const bf16x8*)(&As[cur][(wr + i * 16 + l16) * 32 + quad * 8]);
        #pragma unroll
        for (int j = 0; j < 4; ++j)
            bg[j] = *(const bf16x8*)(&Bs[cur][(wc + j * 16 + l16) * 32 + quad * 8]);
        #pragma unroll
        for (int i = 0; i < 4; ++i)
            #pragma unroll
            for (int j = 0; j < 4; ++j)
                acc[i][j] = __builtin_amdgcn_mfma_f32_16x16x32_bf16(af[i], bg[j], acc[i][j], 0, 0, 0);

        __syncthreads();
        cur ^= 1;
    }

    if (n0 < NHEAD * HDIM) {                       // Q segment
        const int N = NHEAD * HDIM;
        #pragma unroll
        for (int i = 0; i < 4; ++i)
            #pragma unroll
            for (int j = 0; j < 4; ++j) {
                int col = n0 + wc + j * 16 + l16;
                int rowb = m0 + wr + i * 16 + quad * 4;
                #pragma unroll
                for (int r = 0; r < 4; ++r)
                    Cq[(size_t)(rowb + r) * N + col] = f2bf(acc[i][j][r]);
            }
    } else if (n0 < NHEAD * HDIM + NKVH * HDIM) {  // K segment
        const int N = NKVH * HDIM;
        #pragma unroll
        for (int i = 0; i < 4; ++i)
            #pragma unroll
            for (int j = 0; j < 4; ++j) {
                int col = n0 - NHEAD * HDIM + wc + j * 16 + l16;
                int rowb = m0 + wr + i * 16 + quad * 4;
                #pragma unroll
                for (int r = 0; r < 4; ++r)
                    Ck[(size_t)(rowb + r) * N + col] = f2bf(acc[i][j][r]);
            }
    } else {                                       // V segment (transposed out)
        #pragma unroll
        for (int i = 0; i < 4; ++i)
            #pragma unroll
            for (int j = 0; j < 4; ++j) {
                int col = n0 - (NHEAD * HDIM + NKVH * HDIM) + wc + j * 16 + l16;
                int rowb = m0 + wr + i * 16 + quad * 4;
                ushort4 pk;
                pk.x = f2bf(acc[i][j][0]);
                pk.y = f2bf(acc[i][j][1]);
                pk.z = f2bf(acc[i][j][2]);
                pk.w = f2bf(acc[i][j][3]);
                *(ushort4*)&Cvt[(size_t)col * SEQ + rowb] = pk;
            }
    }
}

// Merged in-place RoPE on q (nh=NHEAD) and k (nh=NKVH) in ONE launch.
// idx < SEQ*NHEAD*64 -> q element; else k element. cos[s][d]==cos[s][d+64].
__global__ __launch_bounds__(256) void rope_qk_bf16(unsigned short* __restrict__ q,
                                                    unsigned short* __restrict__ k,
                                                    const float* __restrict__ cosb,
                                                    const float* __restrict__ sinb) {
    int idx = blockIdx.x * 256 + threadIdx.x;
    unsigned short* x; int nh;
    if (idx < SEQ * NHEAD * 64) { x = q; nh = NHEAD; }
    else                        { x = k; nh = NKVH; idx -= SEQ * NHEAD * 64; }
    int d = idx & 63;
    int t = idx >> 6;
    int h = t % nh;
    int s = t / nh;
    float cs = cosb[s * HDIM + d];
    float sn = sinb[s * HDIM + d];
    unsigned short* p = x + (size_t)s * nh * HDIM + h * HDIM + d;
    float x1 = bf2f(p[0]), x2 = bf2f(p[64]);
    p[0]  = f2bf(x1 * cs - x2 * sn);
    p[64] = f2bf(x2 * cs + x1 * sn);
}

// MFMA flash attention. grid (NQT/2, NHEAD), block 256 (4 waves).
// Work-balanced qt pairing + double-buffered K/V staging (validated R3).
__global__ __launch_bounds__(256) void attn_mfma(const unsigned short* __restrict__ qg,
                                                 const unsigned short* __restrict__ kgb,
                                                 const unsigned short* __restrict__ vtg,
                                                 unsigned short* __restrict__ ao) {
    __shared__ unsigned short Ks[2][64 * 128];   // [key][dim], chunk-swizzled, dbuf
    __shared__ unsigned short Vs[2][128 * 64];   // [dim][key], chunk-swizzled, dbuf
    __shared__ unsigned short Ps[4][16 * 64];    // wave-private P, chunk-swizzled
    const int h = blockIdx.y;
    const int kvh = h >> 2;                   // NHEAD/NKVH = 4
    const int tid = threadIdx.x;
    const int w = tid >> 6, lane = tid & 63;
    const int quad = lane >> 4, l16 = lane & 15;
    const int srow16 = tid >> 4, sc16 = tid & 15;   // K staging: 16 rows x 16 chunks / call
    const int sdim8 = tid >> 3, skc8 = tid & 7;     // V staging: 32 dims x 8 chunks / call

    auto stage = [&](int buf, int t) {
        #pragma unroll
        for (int rl = 0; rl < 4; ++rl) {
            int key = rl * 16 + srow16;
            int cg = sc16 ^ (key & 7);   // swizzle on global side
            const unsigned short* gp = kgb + (size_t)(t * 64 + key) * (NKVH * HDIM) + kvh * HDIM + cg * 8;
            GLL16(gp, &Ks[buf][key * 128 + sc16 * 8]);
        }
        #pragma unroll
        for (int rl = 0; rl < 4; ++rl) {
            int dim = rl * 32 + sdim8;
            int kg2 = skc8 ^ (dim & 7);
            const unsigned short* gp = vtg + (size_t)(kvh * HDIM + dim) * SEQ + t * 64 + kg2 * 8;
            GLL16(gp, &Vs[buf][dim * 64 + skc8 * 8]);
        }
    };

    #pragma unroll 1
    for (int ph = 0; ph < 2; ++ph) {
        const int qt = ph ? (NQT - 1 - (int)blockIdx.x) : (int)blockIdx.x;
        const int s0 = qt * 64;

        bf16x8 aq[4];
        {
            const unsigned short* qrowp = qg + (size_t)(s0 + w * 16 + l16) * (NHEAD * HDIM) + h * HDIM;
            #pragma unroll
            for (int ks = 0; ks < 4; ++ks)
                aq[ks] = *(const bf16x8*)(qrowp + ks * 32 + quad * 8);
        }

        floatx4 acc_o[8] = {};
        float m_r[4], l_r[4];
        #pragma unroll
        for (int r = 0; r < 4; ++r) { m_r[r] = -1e30f; l_r[r] = 0.f; }

        stage(0, 0);
        __syncthreads();
        int cur = 0;

        for (int t = 0; t <= qt; ++t) {
            if (t < qt) stage(cur ^ 1, t + 1);
            const unsigned short* Kc = &Ks[cur][0];
            const unsigned short* Vc = &Vs[cur][0];

            floatx4 acc_s[4] = {};
            #pragma unroll
            for (int ks = 0; ks < 4; ++ks)
                #pragma unroll
                for (int jt = 0; jt < 4; ++jt) {
                    bf16x8 bk = *(const bf16x8*)(Kc + (jt * 16 + l16) * 128 +
                                                 (((ks * 4 + quad) ^ (l16 & 7)) * 8));
                    acc_s[jt] = __builtin_amdgcn_mfma_f32_16x16x32_bf16(aq[ks], bk, acc_s[jt], 0, 0, 0);
                }

            float s_v[4][4];
            #pragma unroll
            for (int jt = 0; jt < 4; ++jt)
                #pragma unroll
                for (int r = 0; r < 4; ++r)
                    s_v[jt][r] = acc_s[jt][r] * SCALE;
            if (t == qt) {
                #pragma unroll
                for (int jt = 0; jt < 4; ++jt) {
                    int key = t * 64 + jt * 16 + l16;
                    #pragma unroll
                    for (int r = 0; r < 4; ++r) {
                        int qrow = s0 + w * 16 + quad * 4 + r;
                        if (key > qrow) s_v[jt][r] = -1e30f;
                    }
                }
            }

            float p_v[4][4];
            #pragma unroll
            for (int r = 0; r < 4; ++r) {
                float v = fmaxf(fmaxf(s_v[0][r], s_v[1][r]), fmaxf(s_v[2][r], s_v[3][r]));
                #pragma unroll
                for (int off = 1; off < 16; off <<= 1) v = fmaxf(v, __shfl_xor(v, off));
                float mn = fmaxf(m_r[r], v);
                float alpha = __expf(m_r[r] - mn);
                m_r[r] = mn;
                float sum = 0.f;
                #pragma unroll
                for (int jt = 0; jt < 4; ++jt) { p_v[jt][r] = __expf(s_v[jt][r] - mn); sum += p_v[jt][r]; }
                #pragma unroll
                for (int off = 1; off < 16; off <<= 1) sum += __shfl_xor(sum, off);
                l_r[r] = l_r[r] * alpha + sum;
                #pragma unroll
                for (int nt = 0; nt < 8; ++nt) acc_o[nt][r] *= alpha;
            }

            unsigned short* pw = Ps[w];
            #pragma unroll
            for (int jt = 0; jt < 4; ++jt)
                #pragma unroll
                for (int r = 0; r < 4; ++r) {
                    int row = quad * 4 + r;
                    int c = (2 * jt + (l16 >> 3)) ^ (row & 7);
                    pw[row * 64 + c * 8 + (l16 & 7)] = f2bf(p_v[jt][r]);
                }
            #pragma unroll
            for (int ks = 0; ks < 2; ++ks) {
                bf16x8 ap = *(const bf16x8*)(pw + l16 * 64 + (((ks * 4 + quad) ^ (l16 & 7)) * 8));
                #pragma unroll
                for (int nt = 0; nt < 8; ++nt) {
                    bf16x8 bv = *(const bf16x8*)(Vc + (nt * 16 + l16) * 64 +
                                                 (((ks * 4 + quad) ^ (l16 & 7)) * 8));
                    acc_o[nt] = __builtin_amdgcn_mfma_f32_16x16x32_bf16(ap, bv, acc_o[nt], 0, 0, 0);
                }
            }

            __syncthreads();
            cur ^= 1;
        }

        #pragma unroll
        for (int r = 0; r < 4; ++r) {
            float inv = 1.f / l_r[r];
            int qrow = s0 + w * 16 + quad * 4 + r;
            unsigned short* op = ao + (size_t)qrow * (NHEAD * HDIM) + h * HDIM + l16;
            #pragma unroll
            for (int nt = 0; nt < 8; ++nt)
                op[nt * 16] = f2bf(acc_o[nt][r] * inv);
        }
    }
}

extern "C" void kernel_launch(void* const* d_in, const int* in_sizes, int n_in,
                              void* d_out, int out_size, void* d_ws, size_t ws_size,
                              hipStream_t stream) {
    const float* hidden = (const float*)d_in[0];
    const float* cosb   = (const float*)d_in[1];
    const float* sinb   = (const float*)d_in[2];
    const float* wq     = (const float*)d_in[3];
    const float* wk     = (const float*)d_in[4];
    const float* wv     = (const float*)d_in[5];
    const float* wo     = (const float*)d_in[6];
    // d_in[7..9]: k_cache/v_cache/block_ids — scatter+gather by same ids == identity; unused.

    unsigned short* hb   = (unsigned short*)d_ws;                  // hidden bf16; reused as attn out
    unsigned short* wqkv = hb + (size_t)SEQ * HIDDEN;              // [6144][4096] bf16 (wq;wk;wv); reused for wo
    unsigned short* qb   = wqkv + (size_t)QKV_N * HIDDEN;          // q bf16 [SEQ][4096]
    unsigned short* kb   = qb + (size_t)SEQ * NHEAD * HDIM;        // k bf16 [SEQ][1024]
    unsigned short* vtb  = kb + (size_t)SEQ * NKVH * HDIM;         // v^T bf16 [1024][SEQ]
    unsigned short* ao   = hb;

    dim3 blk(256);

    // 1) Mega-cast: hidden + wq + wk + wv in one launch (segments in block units)
    const int nbH  = SEQ * HIDDEN / 1024;                 // 8192
    const int nbQ  = HIDDEN * HIDDEN / 1024;              // 16384
    const int nbKV = NKVH * HDIM * HIDDEN / 1024;         // 4096 each
    cast4_f32_bf16<<<dim3(nbH + nbQ + 2 * nbKV), blk, 0, stream>>>(
        hidden, hb, nbH,
        wq, wqkv, nbQ,
        wk, wqkv + (size_t)NHEAD * HDIM * HIDDEN, nbKV,
        wv, wqkv + (size_t)(NHEAD + NKVH) * HDIM * HIDDEN);

    // 2) Fused QKV projection (R4-verified 2ph 128^2): grid 48x16 = 768 WGs
    gemm_qkv_mfma<<<dim3(QKV_N / 128, SEQ / 128), blk, 0, stream>>>(hb, wqkv, qb, kb, vtb);

    // 3) wo cast (wqkv region free after QKV GEMM; overlaps rope/attn in-stream)
    cast_f32_bf16<<<dim3(HIDDEN * HIDDEN / 1024), blk, 0, stream>>>(wo, wqkv, HIDDEN * HIDDEN / 4);

    // 4) RoPE on q and k, single launch
    rope_qk_bf16<<<dim3((SEQ * NHEAD * 64 + SEQ * NKVH * 64) / 256), blk, 0, stream>>>(
        qb, kb, cosb, sinb);

    // 5) MFMA flash attention (work-balanced qt pairing, double-buffered staging)
    attn_mfma<<<dim3(NQT / 2, NHEAD), blk, 0, stream>>>(qb, kb, vtb, ao);

    // 6) output projection (fp32 out)
    gemm_nt_mfma<float><<<dim3(HIDDEN / 128, SEQ / 128), blk, 0, stream>>>(
        ao, wqkv, (float*)d_out, SEQ, HIDDEN, NHEAD * HDIM);
}